// Round 12
// baseline (385.297 us; speedup 1.0000x reference)
//
#include <hip/hip_runtime.h>
#include <hip/hip_cooperative_groups.h>
#include <hip/hip_bf16.h>
#include <hip/hip_fp16.h>
#include <math.h>

// GAT forward — atomic-free CSR build, cooperative-fused sort pipeline.
// R25 (this round): budget audit: explainable kernel work ~82us vs 177.6
//      measured -> ~95us is inter-dispatch serialization (~10-15us/launch
//      across 6 dispatches). Fuse s1+s2+p2+p3 into ONE cooperative kernel
//      (512x256, grid.sync between phases, 30KB union LDS = 5 blk/CU >=
//      2/CU co-residency). 6 -> 3 dispatches. Also: ksort's rocprof dur
//      reveals the true (currently hidden) sort cost.
// R24 (WIN 183.1->177.6): LDS-staged p2 (stage+gaddr, linear copy-out) and
//      p3 (stage16, coalesced 2B copy-out) — phase bodies kept verbatim.
// R23 (REGRESS): 8-edge k5 raised VALU cost — 4-edge form kept.
// R22 (WIN 220.9->183.1): counting-sort CSR replaced 1.6M device atomics
//      (hard ~7.4/cy fabric rate; R18/R20/R21 all null).
// R19: per-(node,head)-scaled INT8 feat (absmax 1.95e-3 vs 6.5e-3) kept.
// History: R6 few-cursor global binning disaster; R12 no shfl from exited
// lanes; R13 GEMM-first; R14/R15 head-split failed (per-wave fixed
// overhead); R17 XCD-align null.

#define NEG_SLOPE 0.2f
#define HEADS 4
#define FEAT_OUT 32
#define FEAT_ALL 128
#define IN_FEAT 128
#define KP 136        // LDS K-stride in halves (sf tile only)
#define NBLK1 512     // pack/hist + place blocks
#define NBKT_MAX 512  // max buckets (N<=65536 -> <=512)
#define CHE_MAX 3200  // max edges per p2 chunk (E=1.6M/512=3128)
#define CHB_MAX 6144  // max edges per bucket (Poisson(4096), +32 sigma)

namespace cg = cooperative_groups;

typedef _Float16 half8 __attribute__((ext_vector_type(8)));
typedef float float4v __attribute__((ext_vector_type(4)));
typedef unsigned int uint4v __attribute__((ext_vector_type(4)));

__device__ __forceinline__ float leaky(float v) {
    return v > 0.f ? v : NEG_SLOPE * v;
}

// ---- L1 fused: blocks [0,nG) MFMA GEMM; blocks [nG, nG+NBLK1) pack+hist ----
__global__ __launch_bounds__(256) void k1_fused(
    const int* __restrict__ src, const int* __restrict__ dst, int E,
    int che, int nbkt,
    unsigned int* __restrict__ ds, int* __restrict__ hist,
    const float* __restrict__ h, const float* __restrict__ W,
    const float* __restrict__ attn_l, const float* __restrict__ attn_r,
    unsigned char* __restrict__ feat8, float2* __restrict__ elsc,
    float* __restrict__ er, int N, int nG) {
    __shared__ _Float16 sf[64 * KP];    // 17.4 KB; pack blocks reuse as hist
    const int t = threadIdx.x;

    if ((int)blockIdx.x >= nG) {
        // ---------- pack + per-block bucket histogram ----------
        const int blk = blockIdx.x - nG;        // 0..NBLK1-1
        int* hb = (int*)sf;                     // nbkt bins
        for (int i = t; i < nbkt; i += 256) hb[i] = 0;
        __syncthreads();
        const int e_lo = blk * che;
        int e_hi = e_lo + che; if (e_hi > E) e_hi = E;
        for (int e0 = e_lo + t * 4; e0 < e_hi; e0 += 1024) {
            if (e0 + 3 < e_hi) {
                uint4v s4 = *(const uint4v*)(src + e0);
                uint4v d4 = *(const uint4v*)(dst + e0);
                uint4v r;
#pragma unroll
                for (int j = 0; j < 4; j++) r[j] = (s4[j] << 16) | d4[j];
                *(uint4v*)(ds + e0) = r;
#pragma unroll
                for (int j = 0; j < 4; j++) atomicAdd(&hb[d4[j] >> 7], 1);
            } else {
                for (int e = e0; e < e_hi; ++e) {
                    unsigned s = (unsigned)src[e], d = (unsigned)dst[e];
                    ds[e] = (s << 16) | d;
                    atomicAdd(&hb[d >> 7], 1);
                }
            }
        }
        __syncthreads();
        // column-major hist: hist[b*NBLK1 + blk] (coalesced reads in ksort A)
        for (int i = t; i < nbkt; i += 256) hist[i * NBLK1 + blk] = hb[i];
        return;
    }

    // ---------- GEMM: feat = h@W + epilogue, operands streamed ----------
    const int n0 = blockIdx.x * 64;
    const int wv_ = t >> 6;
    const int lane = t & 63;
    const int m16 = lane & 15;
    const int quad = lane >> 4;
    const int rowA = wv_ * 16 + m16;
    int nA = n0 + rowA; if (nA > N - 1) nA = N - 1;   // clamp: pad rows never stored
    const float* hp = h + (size_t)nA * IN_FEAT + quad * 8;

    float4v acc[8];
#pragma unroll
    for (int i = 0; i < 8; i++) acc[i] = (float4v){0.f, 0.f, 0.f, 0.f};

#pragma unroll
    for (int k0 = 0; k0 < 128; k0 += 32) {
        float4 a0 = *(const float4*)(hp + k0);
        float4 a1 = *(const float4*)(hp + k0 + 4);
        half8 a;
        a[0] = (_Float16)a0.x; a[1] = (_Float16)a0.y;
        a[2] = (_Float16)a0.z; a[3] = (_Float16)a0.w;
        a[4] = (_Float16)a1.x; a[5] = (_Float16)a1.y;
        a[6] = (_Float16)a1.z; a[7] = (_Float16)a1.w;
        const float* wp = W + (size_t)(k0 + quad * 8) * FEAT_ALL + m16;
#pragma unroll
        for (int tN = 0; tN < 8; tN++) {
            const float* wpt = wp + tN * 16;
            half8 b;
            b[0] = (_Float16)wpt[0];
            b[1] = (_Float16)wpt[FEAT_ALL];
            b[2] = (_Float16)wpt[2 * FEAT_ALL];
            b[3] = (_Float16)wpt[3 * FEAT_ALL];
            b[4] = (_Float16)wpt[4 * FEAT_ALL];
            b[5] = (_Float16)wpt[5 * FEAT_ALL];
            b[6] = (_Float16)wpt[6 * FEAT_ALL];
            b[7] = (_Float16)wpt[7 * FEAT_ALL];
            acc[tN] = __builtin_amdgcn_mfma_f32_16x16x32_f16(a, b, acc[tN], 0, 0, 0);
        }
    }

#pragma unroll
    for (int tN = 0; tN < 8; tN++)
#pragma unroll
        for (int r = 0; r < 4; r++) {
            int row = wv_ * 16 + quad * 4 + r;   // C/D: col=lane&15, row=quad*4+reg
            sf[row * KP + tN * 16 + m16] = (_Float16)acc[tN][r];
        }
    __syncthreads();

    // fused epilogue: thread (r,hh) computes el/er/scale over its 32 feats,
    // then packs the same 32 feats to scaled int8.
    {
        int r = t >> 2, hh = t & 3;
        int n = n0 + r;
        if (n < N) {
            const _Float16* sp_ = &sf[r * KP + hh * FEAT_OUT];
            float sl = 0.f, sr = 0.f, mx = 0.f;
#pragma unroll
            for (int f = 0; f < FEAT_OUT; f++) {
                float v = (float)sp_[f];
                sl += v * attn_l[hh * FEAT_OUT + f];
                sr += v * attn_r[hh * FEAT_OUT + f];
                mx = fmaxf(mx, fabsf(v));
            }
            er[n * HEADS + hh] = sr;
            elsc[n * HEADS + hh] = make_float2(sl, mx * (1.f / 127.f));
            const float inv = mx > 0.f ? 127.f / mx : 0.f;
            unsigned int w[8];
#pragma unroll
            for (int k2 = 0; k2 < 8; k2++) {
                unsigned int wv = 0;
#pragma unroll
                for (int j = 0; j < 4; j++) {
                    float v = (float)sp_[k2 * 4 + j];
                    int q = __float2int_rn(v * inv);
                    wv |= ((unsigned int)(q & 0xff)) << (8 * j);
                }
                w[k2] = wv;
            }
            uint4* dp = (uint4*)(feat8 + (size_t)n * FEAT_ALL + hh * 32);
            dp[0] = make_uint4(w[0], w[1], w[2], w[3]);
            dp[1] = make_uint4(w[4], w[5], w[6], w[7]);
        }
    }
}

// ---- ksort: cooperative fusion of s1 + s2 + p2 + p3 (R24 bodies verbatim) ----
__global__ __launch_bounds__(256) void ksort(
    const unsigned int* __restrict__ ds, const int* __restrict__ hist,
    int* __restrict__ base1, int* __restrict__ bb, int* __restrict__ tot,
    unsigned int* __restrict__ srt, unsigned short* __restrict__ slots16,
    unsigned int* __restrict__ rpd, int E, int che, int nbkt, int N) {
    __shared__ union {
        struct { int sm[256]; } a;                                   // A/B scans
        struct {
            int cur[NBKT_MAX]; int gst[NBKT_MAX]; int sm[256];
            unsigned int stage[CHE_MAX]; int gaddr[CHE_MAX];
        } c;                                                          // place
        struct { int h2[128]; int nbuf[128]; unsigned short stage16[CHB_MAX]; } d; // CSR
    } u;                                                              // ~30 KB
    const int t = threadIdx.x;
    const int blk = blockIdx.x;
    cg::grid_group grid = cg::this_grid();

    // ---- phase A (s1): per-bucket exclusive prefix over block hists ----
    if (blk < nbkt) {
        const int b = blk;
        const int v0 = hist[b * NBLK1 + 2 * t];
        const int v1 = hist[b * NBLK1 + 2 * t + 1];
        const int s = v0 + v1;
        u.a.sm[t] = s; __syncthreads();
        for (int off = 1; off < 256; off <<= 1) {
            int x = (t >= off) ? u.a.sm[t - off] : 0;
            __syncthreads();
            u.a.sm[t] += x;
            __syncthreads();
        }
        const int excl = u.a.sm[t] - s;
        base1[(2 * t) * nbkt + b] = excl;         // row-major for phase C
        base1[(2 * t + 1) * nbkt + b] = excl + v0;
        if (t == 255) tot[b] = u.a.sm[255];
    }
    grid.sync();

    // ---- phase B (s2): bucket bases bb[0..nbkt] ----
    if (blk == 0) {
        const int v0 = (2 * t < nbkt) ? tot[2 * t] : 0;
        const int v1 = (2 * t + 1 < nbkt) ? tot[2 * t + 1] : 0;
        const int s = v0 + v1;
        u.a.sm[t] = s; __syncthreads();
        for (int off = 1; off < 256; off <<= 1) {
            int x = (t >= off) ? u.a.sm[t - off] : 0;
            __syncthreads();
            u.a.sm[t] += x;
            __syncthreads();
        }
        const int excl = u.a.sm[t] - s;
        if (2 * t <= nbkt) bb[2 * t] = excl;
        if (2 * t + 1 <= nbkt) bb[2 * t + 1] = excl + v0;
    }
    grid.sync();

    // ---- phase C (p2): LDS-staged bucket sort of chunk, linear copy-out ----
    {
        const int e_lo = blk * che;
        int e_hi = e_lo + che; if (e_hi > E) e_hi = E;
        int cnt = e_hi - e_lo; if (cnt < 0) cnt = 0;
        if (che <= CHE_MAX) {
            const int b0 = 2 * t, b1 = 2 * t + 1;
            const int h0 = (b0 < nbkt) ? hist[b0 * NBLK1 + blk] : 0;
            const int h1 = (b1 < nbkt) ? hist[b1 * NBLK1 + blk] : 0;
            const int s = h0 + h1;
            u.c.sm[t] = s; __syncthreads();
            for (int off = 1; off < 256; off <<= 1) {
                int x = (t >= off) ? u.c.sm[t - off] : 0;
                __syncthreads();
                u.c.sm[t] += x;
                __syncthreads();
            }
            const int excl = u.c.sm[t] - s;
            if (b0 < nbkt) {
                u.c.cur[b0] = excl;
                u.c.gst[b0] = bb[b0] + base1[blk * nbkt + b0] - excl;
            }
            if (b1 < nbkt) {
                u.c.cur[b1] = excl + h0;
                u.c.gst[b1] = bb[b1] + base1[blk * nbkt + b1] - (excl + h0);
            }
            __syncthreads();
            for (int e0 = e_lo + t * 4; e0 < e_hi; e0 += 1024) {
                if (e0 + 3 < e_hi) {
                    uint4v q = *(const uint4v*)(ds + e0);
#pragma unroll
                    for (int j = 0; j < 4; j++) {
                        int b = (int)(q[j] & 0xffffu) >> 7;
                        int r = atomicAdd(&u.c.cur[b], 1);
                        u.c.stage[r] = q[j];
                        u.c.gaddr[r] = u.c.gst[b] + r;
                    }
                } else {
                    for (int e = e0; e < e_hi; ++e) {
                        unsigned q = ds[e];
                        int b = (int)(q & 0xffffu) >> 7;
                        int r = atomicAdd(&u.c.cur[b], 1);
                        u.c.stage[r] = q;
                        u.c.gaddr[r] = u.c.gst[b] + r;
                    }
                }
            }
            __syncthreads();
            for (int i = t; i < cnt; i += 256)
                srt[u.c.gaddr[i]] = u.c.stage[i];
        } else {
            // fallback: direct global scatter
            for (int i = t; i < nbkt; i += 256)
                u.c.cur[i] = bb[i] + base1[blk * nbkt + i];
            __syncthreads();
            for (int e = e_lo + t; e < e_hi; e += 256) {
                unsigned q = ds[e];
                int b = (int)(q & 0xffffu) >> 7;
                int idx = atomicAdd(&u.c.cur[b], 1);
                srt[idx] = q;
            }
        }
    }
    grid.sync();

    // ---- phase D (p3): per-bucket exact CSR + staged slots16 ----
    if (blk < nbkt) {
        const int b = blk;
        const int s0 = bb[b];
        const int M = bb[b + 1] - s0;
        const int lo = b << 7;
        if (t < 128) u.d.h2[t] = 0;
        __syncthreads();
        for (int i = t; i < M; i += 256) {
            unsigned q = srt[s0 + i];
            atomicAdd(&u.d.h2[(int)(q & 0xffffu) - lo], 1);
        }
        __syncthreads();
        int hv = 0;
        if (t < 128) hv = u.d.h2[t];
        for (int off = 1; off < 128; off <<= 1) {
            int x = 0;
            if (t < 128 && t >= off) x = u.d.h2[t - off];
            __syncthreads();
            if (t < 128) u.d.h2[t] += x;
            __syncthreads();
        }
        if (t < 128) {
            const int excl = u.d.h2[t] - hv;
            u.d.nbuf[t] = excl;
            const int n = lo + t;
            if (n < N) {
                int dg = hv > 255 ? 255 : hv;
                rpd[n] = ((unsigned)(s0 + excl) << 8) | (unsigned)dg;
            }
        }
        __syncthreads();
        if (t < 128) u.d.h2[t] = u.d.nbuf[t];
        __syncthreads();
        if (M <= CHB_MAX) {
            for (int i = t; i < M; i += 256) {
                unsigned q = srt[s0 + i];
                int n7 = (int)(q & 0xffffu) - lo;
                int r = atomicAdd(&u.d.h2[n7], 1);
                u.d.stage16[r] = (unsigned short)(q >> 16);
            }
            __syncthreads();
            for (int i = t; i < M; i += 256)          // coalesced 2B copy-out
                slots16[s0 + i] = u.d.stage16[i];
        } else {
            for (int i = t; i < M; i += 256) {
                unsigned q = srt[s0 + i];
                int n7 = (int)(q & 0xffffu) - lo;
                int r = atomicAdd(&u.d.h2[n7], 1);
                slots16[s0 + r] = (unsigned short)(q >> 16);
            }
        }
    }
}

// ---- K5: wave-per-node single-pass aggregate (R22-proven 4-edge form) ----
__global__ __launch_bounds__(256) void k5_node(
    const unsigned int* __restrict__ rpd, const unsigned short* __restrict__ slots16,
    const float2* __restrict__ elsc, const float* __restrict__ er,
    const unsigned char* __restrict__ feat8, const float* __restrict__ bias,
    float* __restrict__ out, int N) {
    const int lane = threadIdx.x & 63;
    const int p = blockIdx.x & 7;
    const int g = blockIdx.x >> 3;
    const int NPER = (N + 7) >> 3;
    const int hi = ((p + 1) * NPER < N) ? (p + 1) * NPER : N;
    const int n = p * NPER + g * 4 + (threadIdx.x >> 6);
    if (n >= hi) return;                 // wave-uniform exit
    const unsigned rd = rpd[n];
    const int deg = (int)(rd & 0xffu);
    const unsigned short* sp = slots16 + (rd >> 8);

    const int sub4 = lane >> 4;     // edge within group of 4
    const int q4 = lane & 15;       // feats 8q4 .. 8q4+7
    const int hh = q4 >> 2;         // head of those feats
    const float ernh = er[n * HEADS + hh];

    float acc[8];
#pragma unroll
    for (int j = 0; j < 8; j++) acc[j] = 0.f;
    float den = 0.f;

#pragma unroll 4
    for (int i = sub4; i < deg; i += 4) {
        int s = (int)sp[i];                       // 16-lane broadcast load
        float2 es = elsc[s * HEADS + hh];         // {el, scale/127}
        float ex = __expf(leaky(es.x + ernh));
        uint2 u = *(const uint2*)(feat8 + (size_t)s * FEAT_ALL + q4 * 8);
        float exs = ex * es.y;
        den += ex;
        union { uint2 v; signed char b[8]; } cv;
        cv.v = u;
        acc[0] += exs * (float)cv.b[0];
        acc[1] += exs * (float)cv.b[1];
        acc[2] += exs * (float)cv.b[2];
        acc[3] += exs * (float)cv.b[3];
        acc[4] += exs * (float)cv.b[4];
        acc[5] += exs * (float)cv.b[5];
        acc[6] += exs * (float)cv.b[6];
        acc[7] += exs * (float)cv.b[7];
    }

    // joint reduction over the 4 edge-subgroups
#pragma unroll
    for (int j = 0; j < 8; j++) {
        acc[j] += __shfl_xor(acc[j], 16);
        acc[j] += __shfl_xor(acc[j], 32);
    }
    den += __shfl_xor(den, 16);
    den += __shfl_xor(den, 32);
    const float idh = 1.f / fmaxf(den, 1e-9f);

    // bias + relu (per head), then mean over heads (lanes q4, q4^4, q4^8, q4^12)
    const float4 b0 = ((const float4*)bias)[q4 * 2];
    const float4 b1 = ((const float4*)bias)[q4 * 2 + 1];
    float v[8];
    v[0] = fmaxf(acc[0] * idh + b0.x, 0.f); v[1] = fmaxf(acc[1] * idh + b0.y, 0.f);
    v[2] = fmaxf(acc[2] * idh + b0.z, 0.f); v[3] = fmaxf(acc[3] * idh + b0.w, 0.f);
    v[4] = fmaxf(acc[4] * idh + b1.x, 0.f); v[5] = fmaxf(acc[5] * idh + b1.y, 0.f);
    v[6] = fmaxf(acc[6] * idh + b1.z, 0.f); v[7] = fmaxf(acc[7] * idh + b1.w, 0.f);
#pragma unroll
    for (int j = 0; j < 8; j++) {
        v[j] += __shfl_xor(v[j], 4);
        v[j] += __shfl_xor(v[j], 8);
    }
    if (lane < 4) {
        float4 o0 = make_float4(v[0] * 0.25f, v[1] * 0.25f, v[2] * 0.25f, v[3] * 0.25f);
        float4 o1 = make_float4(v[4] * 0.25f, v[5] * 0.25f, v[6] * 0.25f, v[7] * 0.25f);
        float* op = out + (size_t)n * FEAT_OUT + lane * 8;
        ((float4*)op)[0] = o0;
        ((float4*)op)[1] = o1;
    }
}

extern "C" void kernel_launch(void* const* d_in, const int* in_sizes, int n_in,
                              void* d_out, int out_size, void* d_ws, size_t ws_size,
                              hipStream_t stream) {
    const float* h      = (const float*)d_in[0];
    const float* W      = (const float*)d_in[1];
    const float* attn_l = (const float*)d_in[2];
    const float* attn_r = (const float*)d_in[3];
    const float* bias   = (const float*)d_in[4];
    const int*   src    = (const int*)d_in[5];
    const int*   dst    = (const int*)d_in[6];
    float* out = (float*)d_out;

    const int N = in_sizes[0] / IN_FEAT;
    int E = in_sizes[5];
    int nbkt = (N + 127) >> 7;                             // 391 for N=50000
    int che = (((E + NBLK1 - 1) / NBLK1) + 3) & ~3;        // chunk edges, x4

    // workspace layout (256B-aligned slabs)
    char* w = (char*)d_ws;
    auto alloc = [&](size_t bytes) { char* r = w; w += (bytes + 255) & ~(size_t)255; return r; };
    unsigned char* feat8   = (unsigned char*)alloc((size_t)N * FEAT_ALL);
    float2*        elsc    = (float2*)alloc((size_t)N * HEADS * sizeof(float2));
    float*         er      = (float*)alloc((size_t)N * HEADS * sizeof(float));
    unsigned int*  rpd     = (unsigned int*)alloc((size_t)N * 4);
    unsigned int*  ds      = (unsigned int*)alloc((size_t)E * 4);
    unsigned int*  srt     = (unsigned int*)alloc((size_t)E * 4);
    unsigned short* slots16 = (unsigned short*)alloc((size_t)E * 2);
    int*           hist    = (int*)alloc((size_t)NBLK1 * nbkt * 4);
    int*           base1   = (int*)alloc((size_t)NBLK1 * nbkt * 4);
    int*           tot     = (int*)alloc((size_t)nbkt * 4);
    int*           bb      = (int*)alloc((size_t)(nbkt + 1) * 4);
    int N_ = N;

    const int nG = (N + 63) / 64;
    k1_fused<<<nG + NBLK1, 256, 0, stream>>>(src, dst, E, che, nbkt, ds, hist,
                                             h, W, attn_l, attn_r,
                                             feat8, elsc, er, N, nG);

    void* args[] = {(void*)&ds, (void*)&hist, (void*)&base1, (void*)&bb,
                    (void*)&tot, (void*)&srt, (void*)&slots16, (void*)&rpd,
                    (void*)&E, (void*)&che, (void*)&nbkt, (void*)&N_};
    hipLaunchCooperativeKernel((void*)ksort, dim3(NBLK1), dim3(256), args, 0, stream);

    const int NPER = (N + 7) >> 3;
    const int nb5 = 8 * ((NPER + 3) / 4);
    k5_node<<<nb5, 256, 0, stream>>>(rpd, slots16, elsc, er, feat8, bias, out, N);
}

// Round 13
// 189.188 us; speedup vs baseline: 2.0366x; 2.0366x over previous
//
#include <hip/hip_runtime.h>
#include <hip/hip_bf16.h>
#include <hip/hip_fp16.h>
#include <math.h>

// GAT forward — atomic-free CSR build, 4-dispatch pipeline, no global sync.
// R26 (this round): R25's ksort proved sort WORK is ~10-15us and grid.sync
//      costs ~70us/barrier (device-wide spin = the 7/cy fabric wall) ->
//      reduce dispatches WITHOUT sync: (a) s2 eliminated — p2/k5 recompute
//      bucket bases locally from tot (prior-dispatch data, no visibility
//      hazard); (b) p3 fused into k5_bkt: block = (bucket, quarter) = 32
//      nodes; builds mini-CSR in LDS from srt segment, aggregates with
//      slot ids from LDS. 6 -> 4 dispatches (~15-19us gap each), slots16
//      round-trip gone, occupancy 64->76%.
// R25 (REGRESS 385): cooperative grid.sync = 70us/barrier. NEVER spin-sync.
// R24 (WIN 177.6): LDS-staged p2 copy-out (kept verbatim).
// R23 (REGRESS): 8-edge k5 — 4-edge/16-lane form kept.
// R22 (WIN 183.1): counting-sort CSR replaced 1.6M device atomics.
// R19: per-(node,head)-scaled INT8 feat (absmax 1.95e-3 vs 6.5e-3) kept.
// History: R6 global few-cursor binning disaster; R12 no shfl from exited
// lanes; R13 GEMM-first; R14/R15 head-split fail; R17 XCD-align null;
// R18/R20/R21 atomic tuning nulls (fabric wall).

#define NEG_SLOPE 0.2f
#define HEADS 4
#define FEAT_OUT 32
#define FEAT_ALL 128
#define IN_FEAT 128
#define KP 136        // LDS K-stride in halves (sf tile only)
#define NBLK1 512     // pack/hist + place blocks
#define NBKT_MAX 512  // max buckets (N<=65536 -> <=512)
#define CHE_MAX 3200  // max edges per p2 chunk (E=1.6M/512=3128)
#define QCAP 2048     // max edges per 32-node quarter (Poisson(1024)+tail)

typedef _Float16 half8 __attribute__((ext_vector_type(8)));
typedef float float4v __attribute__((ext_vector_type(4)));
typedef unsigned int uint4v __attribute__((ext_vector_type(4)));

__device__ __forceinline__ float leaky(float v) {
    return v > 0.f ? v : NEG_SLOPE * v;
}

// ---- L1 fused: blocks [0,nG) MFMA GEMM; blocks [nG, nG+NBLK1) pack+hist ----
__global__ __launch_bounds__(256) void k1_fused(
    const int* __restrict__ src, const int* __restrict__ dst, int E,
    int che, int nbkt,
    unsigned int* __restrict__ ds, int* __restrict__ hist,
    const float* __restrict__ h, const float* __restrict__ W,
    const float* __restrict__ attn_l, const float* __restrict__ attn_r,
    unsigned char* __restrict__ feat8, float2* __restrict__ elsc,
    float* __restrict__ er, int N, int nG) {
    __shared__ _Float16 sf[64 * KP];    // 17.4 KB; pack blocks reuse as hist
    const int t = threadIdx.x;

    if ((int)blockIdx.x >= nG) {
        // ---------- pack + per-block bucket histogram ----------
        const int blk = blockIdx.x - nG;        // 0..NBLK1-1
        int* hb = (int*)sf;                     // nbkt bins
        for (int i = t; i < nbkt; i += 256) hb[i] = 0;
        __syncthreads();
        const int e_lo = blk * che;
        int e_hi = e_lo + che; if (e_hi > E) e_hi = E;
        for (int e0 = e_lo + t * 4; e0 < e_hi; e0 += 1024) {
            if (e0 + 3 < e_hi) {
                uint4v s4 = *(const uint4v*)(src + e0);
                uint4v d4 = *(const uint4v*)(dst + e0);
                uint4v r;
#pragma unroll
                for (int j = 0; j < 4; j++) r[j] = (s4[j] << 16) | d4[j];
                *(uint4v*)(ds + e0) = r;
#pragma unroll
                for (int j = 0; j < 4; j++) atomicAdd(&hb[d4[j] >> 7], 1);
            } else {
                for (int e = e0; e < e_hi; ++e) {
                    unsigned s = (unsigned)src[e], d = (unsigned)dst[e];
                    ds[e] = (s << 16) | d;
                    atomicAdd(&hb[d >> 7], 1);
                }
            }
        }
        __syncthreads();
        // column-major hist: hist[b*NBLK1 + blk] (coalesced reads in s1)
        for (int i = t; i < nbkt; i += 256) hist[i * NBLK1 + blk] = hb[i];
        return;
    }

    // ---------- GEMM: feat = h@W + epilogue, operands streamed ----------
    const int n0 = blockIdx.x * 64;
    const int wv_ = t >> 6;
    const int lane = t & 63;
    const int m16 = lane & 15;
    const int quad = lane >> 4;
    const int rowA = wv_ * 16 + m16;
    int nA = n0 + rowA; if (nA > N - 1) nA = N - 1;   // clamp: pad rows never stored
    const float* hp = h + (size_t)nA * IN_FEAT + quad * 8;

    float4v acc[8];
#pragma unroll
    for (int i = 0; i < 8; i++) acc[i] = (float4v){0.f, 0.f, 0.f, 0.f};

#pragma unroll
    for (int k0 = 0; k0 < 128; k0 += 32) {
        float4 a0 = *(const float4*)(hp + k0);
        float4 a1 = *(const float4*)(hp + k0 + 4);
        half8 a;
        a[0] = (_Float16)a0.x; a[1] = (_Float16)a0.y;
        a[2] = (_Float16)a0.z; a[3] = (_Float16)a0.w;
        a[4] = (_Float16)a1.x; a[5] = (_Float16)a1.y;
        a[6] = (_Float16)a1.z; a[7] = (_Float16)a1.w;
        const float* wp = W + (size_t)(k0 + quad * 8) * FEAT_ALL + m16;
#pragma unroll
        for (int tN = 0; tN < 8; tN++) {
            const float* wpt = wp + tN * 16;
            half8 b;
            b[0] = (_Float16)wpt[0];
            b[1] = (_Float16)wpt[FEAT_ALL];
            b[2] = (_Float16)wpt[2 * FEAT_ALL];
            b[3] = (_Float16)wpt[3 * FEAT_ALL];
            b[4] = (_Float16)wpt[4 * FEAT_ALL];
            b[5] = (_Float16)wpt[5 * FEAT_ALL];
            b[6] = (_Float16)wpt[6 * FEAT_ALL];
            b[7] = (_Float16)wpt[7 * FEAT_ALL];
            acc[tN] = __builtin_amdgcn_mfma_f32_16x16x32_f16(a, b, acc[tN], 0, 0, 0);
        }
    }

#pragma unroll
    for (int tN = 0; tN < 8; tN++)
#pragma unroll
        for (int r = 0; r < 4; r++) {
            int row = wv_ * 16 + quad * 4 + r;   // C/D: col=lane&15, row=quad*4+reg
            sf[row * KP + tN * 16 + m16] = (_Float16)acc[tN][r];
        }
    __syncthreads();

    // fused epilogue: thread (r,hh) computes el/er/scale over its 32 feats,
    // then packs the same 32 feats to scaled int8.
    {
        int r = t >> 2, hh = t & 3;
        int n = n0 + r;
        if (n < N) {
            const _Float16* sp_ = &sf[r * KP + hh * FEAT_OUT];
            float sl = 0.f, sr = 0.f, mx = 0.f;
#pragma unroll
            for (int f = 0; f < FEAT_OUT; f++) {
                float v = (float)sp_[f];
                sl += v * attn_l[hh * FEAT_OUT + f];
                sr += v * attn_r[hh * FEAT_OUT + f];
                mx = fmaxf(mx, fabsf(v));
            }
            er[n * HEADS + hh] = sr;
            elsc[n * HEADS + hh] = make_float2(sl, mx * (1.f / 127.f));
            const float inv = mx > 0.f ? 127.f / mx : 0.f;
            unsigned int w[8];
#pragma unroll
            for (int k2 = 0; k2 < 8; k2++) {
                unsigned int wv = 0;
#pragma unroll
                for (int j = 0; j < 4; j++) {
                    float v = (float)sp_[k2 * 4 + j];
                    int q = __float2int_rn(v * inv);
                    wv |= ((unsigned int)(q & 0xff)) << (8 * j);
                }
                w[k2] = wv;
            }
            uint4* dp = (uint4*)(feat8 + (size_t)n * FEAT_ALL + hh * 32);
            dp[0] = make_uint4(w[0], w[1], w[2], w[3]);
            dp[1] = make_uint4(w[4], w[5], w[6], w[7]);
        }
    }
}

// ---- s1: per-bucket exclusive prefix over the 512 block histograms ----
__global__ __launch_bounds__(256) void s1_scan(
    const int* __restrict__ hist, int* __restrict__ base1,
    int* __restrict__ tot, int nbkt) {
    __shared__ int sm[256];
    const int b = blockIdx.x;       // bucket
    const int t = threadIdx.x;
    const int v0 = hist[b * NBLK1 + 2 * t];
    const int v1 = hist[b * NBLK1 + 2 * t + 1];
    const int s = v0 + v1;
    sm[t] = s; __syncthreads();
    for (int off = 1; off < 256; off <<= 1) {
        int x = (t >= off) ? sm[t - off] : 0;
        __syncthreads();
        sm[t] += x;
        __syncthreads();
    }
    const int excl = sm[t] - s;
    base1[(2 * t) * nbkt + b] = excl;         // row-major for p2
    base1[(2 * t + 1) * nbkt + b] = excl + v0;
    if (t == 255) tot[b] = sm[255];
}

// ---- p2: local bucket-base scan + LDS-staged place + linear copy-out ----
__global__ __launch_bounds__(256) void p2_place(
    const unsigned int* __restrict__ ds, const int* __restrict__ hist,
    const int* __restrict__ base1, const int* __restrict__ tot,
    unsigned int* __restrict__ srt, int E, int che, int nbkt) {
    __shared__ int cur[NBKT_MAX];
    __shared__ int gst[NBKT_MAX];
    __shared__ int bbloc[NBKT_MAX];
    __shared__ int sm[256];
    __shared__ unsigned int stage[CHE_MAX];
    __shared__ int gaddr[CHE_MAX];
    const int t = threadIdx.x;
    const int blk = blockIdx.x;
    const int e_lo = blk * che;
    int e_hi = e_lo + che; if (e_hi > E) e_hi = E;
    int cnt = e_hi - e_lo; if (cnt < 0) cnt = 0;

    // bbloc = exclusive scan of tot (local recompute; replaces s2 dispatch)
    {
        const int v0 = (2 * t < nbkt) ? tot[2 * t] : 0;
        const int v1 = (2 * t + 1 < nbkt) ? tot[2 * t + 1] : 0;
        const int s = v0 + v1;
        sm[t] = s; __syncthreads();
        for (int off = 1; off < 256; off <<= 1) {
            int x = (t >= off) ? sm[t - off] : 0;
            __syncthreads();
            sm[t] += x;
            __syncthreads();
        }
        const int excl = sm[t] - s;
        if (2 * t < nbkt) bbloc[2 * t] = excl;
        if (2 * t + 1 < nbkt) bbloc[2 * t + 1] = excl + v0;
    }
    __syncthreads();

    if (che <= CHE_MAX) {
        // local hist column -> exclusive prefix (2 elems/thread)
        const int b0 = 2 * t, b1 = 2 * t + 1;
        const int h0 = (b0 < nbkt) ? hist[b0 * NBLK1 + blk] : 0;
        const int h1 = (b1 < nbkt) ? hist[b1 * NBLK1 + blk] : 0;
        const int s = h0 + h1;
        sm[t] = s; __syncthreads();
        for (int off = 1; off < 256; off <<= 1) {
            int x = (t >= off) ? sm[t - off] : 0;
            __syncthreads();
            sm[t] += x;
            __syncthreads();
        }
        const int excl = sm[t] - s;
        if (b0 < nbkt) {
            cur[b0] = excl;
            gst[b0] = bbloc[b0] + base1[blk * nbkt + b0] - excl;   // gaddr = gst + r
        }
        if (b1 < nbkt) {
            cur[b1] = excl + h0;
            gst[b1] = bbloc[b1] + base1[blk * nbkt + b1] - (excl + h0);
        }
        __syncthreads();
        for (int e0 = e_lo + t * 4; e0 < e_hi; e0 += 1024) {
            if (e0 + 3 < e_hi) {
                uint4v q = *(const uint4v*)(ds + e0);
#pragma unroll
                for (int j = 0; j < 4; j++) {
                    int b = (int)(q[j] & 0xffffu) >> 7;
                    int r = atomicAdd(&cur[b], 1);
                    stage[r] = q[j];
                    gaddr[r] = gst[b] + r;
                }
            } else {
                for (int e = e0; e < e_hi; ++e) {
                    unsigned q = ds[e];
                    int b = (int)(q & 0xffffu) >> 7;
                    int r = atomicAdd(&cur[b], 1);
                    stage[r] = q;
                    gaddr[r] = gst[b] + r;
                }
            }
        }
        __syncthreads();
        for (int i = t; i < cnt; i += 256)
            srt[gaddr[i]] = stage[i];
    } else {
        // fallback: direct global scatter
        for (int i = t; i < nbkt; i += 256)
            cur[i] = bbloc[i] + base1[blk * nbkt + i];
        __syncthreads();
        for (int e = e_lo + t; e < e_hi; e += 256) {
            unsigned q = ds[e];
            int b = (int)(q & 0xffffu) >> 7;
            int idx = atomicAdd(&cur[b], 1);
            srt[idx] = q;
        }
    }
}

// ---- k5_bkt: fused CSR-build + aggregate. Block = (bucket, quarter) ----
// 32 nodes/block; mini-CSR (hist+scan+stage16 scatter) in LDS from the
// bucket's contiguous srt segment, then 4 waves x 8 nodes each run the
// R22-proven 4-edge/16-lane aggregation with slot ids read from LDS.
// XCD-local id mapping: the 4 quarter-blocks of a bucket share one XCD,
// so the srt segment is fetched once into that XCD's L2.
__global__ __launch_bounds__(256) void k5_bkt(
    const unsigned int* __restrict__ srt, const int* __restrict__ tot,
    const float2* __restrict__ elsc, const float* __restrict__ er,
    const unsigned char* __restrict__ feat8, const float* __restrict__ bias,
    float* __restrict__ out, int N, int nbkt) {
    __shared__ int red[256];
    __shared__ int rowptr[33];
    __shared__ int curq[32];
    __shared__ unsigned short stage16[QCAP];
    const int t = threadIdx.x;
    const int p = blockIdx.x & 7;
    const int kk_ = blockIdx.x >> 3;
    const int b = (kk_ >> 2) * 8 + p;
    const int qtr = kk_ & 3;
    if (b >= nbkt) return;               // block-uniform exit

    // s0 = sum tot[0..b-1] (local reduce; replaces s2/bb)
    int partial = 0;
    for (int i = t; i < b; i += 256) partial += tot[i];
    red[t] = partial; __syncthreads();
    for (int off = 128; off > 0; off >>= 1) {
        if (t < off) red[t] += red[t + off];
        __syncthreads();
    }
    const int s0 = red[0];
    const int M = tot[b];
    const int lo = (b << 7) + qtr * 32;  // first node of this quarter

    // pass1: histogram my 32 nodes over the bucket segment
    if (t < 32) curq[t] = 0;
    __syncthreads();
    for (int i = t; i < M; i += 256) {
        int u = (int)(srt[s0 + i] & 0xffffu) - lo;
        if ((unsigned)u < 32u) atomicAdd(&curq[u], 1);
    }
    __syncthreads();
    if (t == 0) {                        // tiny serial scan of 32 bins
        int acc = 0;
#pragma unroll
        for (int j = 0; j < 32; j++) { rowptr[j] = acc; acc += curq[j]; }
        rowptr[32] = acc;
    }
    __syncthreads();
    const int Mq = rowptr[32];
    const bool staged = (Mq <= QCAP);
    if (staged) {
        if (t < 32) curq[t] = rowptr[t];
        __syncthreads();
        for (int i = t; i < M; i += 256) {
            unsigned q = srt[s0 + i];
            int u = (int)(q & 0xffffu) - lo;
            if ((unsigned)u < 32u) {
                int r = atomicAdd(&curq[u], 1);
                stage16[r] = (unsigned short)(q >> 16);
            }
        }
        __syncthreads();
    }

    // aggregate: wave wv handles nodes lo+wv*8 .. lo+wv*8+7 sequentially
    const int lane = t & 63;
    const int wv = t >> 6;
    const int sub4 = lane >> 4;     // edge within group of 4
    const int q4 = lane & 15;       // feats 8q4 .. 8q4+7
    const int hh = q4 >> 2;         // head of those feats
    const float4 b0v = ((const float4*)bias)[q4 * 2];
    const float4 b1v = ((const float4*)bias)[q4 * 2 + 1];

    for (int kk = 0; kk < 8; kk++) {
        const int u = wv * 8 + kk;
        const int n = lo + u;
        if (n >= N) continue;            // wave-uniform (depends on wv,kk only)
        const int rp = rowptr[u];
        const int deg = rowptr[u + 1] - rp;
        const float ernh = er[n * HEADS + hh];

        float acc[8];
#pragma unroll
        for (int j = 0; j < 8; j++) acc[j] = 0.f;
        float den = 0.f;

        if (staged) {
#pragma unroll 4
            for (int i = sub4; i < deg; i += 4) {
                int s = (int)stage16[rp + i];             // LDS broadcast
                float2 es = elsc[s * HEADS + hh];         // {el, scale/127}
                float ex = __expf(leaky(es.x + ernh));
                uint2 uv = *(const uint2*)(feat8 + (size_t)s * FEAT_ALL + q4 * 8);
                float exs = ex * es.y;
                den += ex;
                union { uint2 v; signed char c[8]; } cv;
                cv.v = uv;
                acc[0] += exs * (float)cv.c[0];
                acc[1] += exs * (float)cv.c[1];
                acc[2] += exs * (float)cv.c[2];
                acc[3] += exs * (float)cv.c[3];
                acc[4] += exs * (float)cv.c[4];
                acc[5] += exs * (float)cv.c[5];
                acc[6] += exs * (float)cv.c[6];
                acc[7] += exs * (float)cv.c[7];
            }
        } else {
            // overflow fallback (never hit statistically): filter-scan srt
            for (int i = sub4; i < M; i += 4) {
                unsigned q = srt[s0 + i];
                if ((int)(q & 0xffffu) != n) continue;
                int s = (int)(q >> 16);
                float2 es = elsc[s * HEADS + hh];
                float ex = __expf(leaky(es.x + ernh));
                uint2 uv = *(const uint2*)(feat8 + (size_t)s * FEAT_ALL + q4 * 8);
                float exs = ex * es.y;
                den += ex;
                union { uint2 v; signed char c[8]; } cv;
                cv.v = uv;
                acc[0] += exs * (float)cv.c[0];
                acc[1] += exs * (float)cv.c[1];
                acc[2] += exs * (float)cv.c[2];
                acc[3] += exs * (float)cv.c[3];
                acc[4] += exs * (float)cv.c[4];
                acc[5] += exs * (float)cv.c[5];
                acc[6] += exs * (float)cv.c[6];
                acc[7] += exs * (float)cv.c[7];
            }
        }

        // joint reduction over the 4 edge-subgroups
#pragma unroll
        for (int j = 0; j < 8; j++) {
            acc[j] += __shfl_xor(acc[j], 16);
            acc[j] += __shfl_xor(acc[j], 32);
        }
        den += __shfl_xor(den, 16);
        den += __shfl_xor(den, 32);
        const float idh = 1.f / fmaxf(den, 1e-9f);

        float v[8];
        v[0] = fmaxf(acc[0] * idh + b0v.x, 0.f); v[1] = fmaxf(acc[1] * idh + b0v.y, 0.f);
        v[2] = fmaxf(acc[2] * idh + b0v.z, 0.f); v[3] = fmaxf(acc[3] * idh + b0v.w, 0.f);
        v[4] = fmaxf(acc[4] * idh + b1v.x, 0.f); v[5] = fmaxf(acc[5] * idh + b1v.y, 0.f);
        v[6] = fmaxf(acc[6] * idh + b1v.z, 0.f); v[7] = fmaxf(acc[7] * idh + b1v.w, 0.f);
#pragma unroll
        for (int j = 0; j < 8; j++) {
            v[j] += __shfl_xor(v[j], 4);
            v[j] += __shfl_xor(v[j], 8);
        }
        if (lane < 4) {
            float4 o0 = make_float4(v[0] * 0.25f, v[1] * 0.25f, v[2] * 0.25f, v[3] * 0.25f);
            float4 o1 = make_float4(v[4] * 0.25f, v[5] * 0.25f, v[6] * 0.25f, v[7] * 0.25f);
            float* op = out + (size_t)n * FEAT_OUT + lane * 8;
            ((float4*)op)[0] = o0;
            ((float4*)op)[1] = o1;
        }
    }
}

extern "C" void kernel_launch(void* const* d_in, const int* in_sizes, int n_in,
                              void* d_out, int out_size, void* d_ws, size_t ws_size,
                              hipStream_t stream) {
    const float* h      = (const float*)d_in[0];
    const float* W      = (const float*)d_in[1];
    const float* attn_l = (const float*)d_in[2];
    const float* attn_r = (const float*)d_in[3];
    const float* bias   = (const float*)d_in[4];
    const int*   src    = (const int*)d_in[5];
    const int*   dst    = (const int*)d_in[6];
    float* out = (float*)d_out;

    const int N = in_sizes[0] / IN_FEAT;
    const int E = in_sizes[5];
    const int nbkt = (N + 127) >> 7;                       // 391 for N=50000
    const int che = (((E + NBLK1 - 1) / NBLK1) + 3) & ~3;  // chunk edges, x4

    // workspace layout (256B-aligned slabs)
    char* w = (char*)d_ws;
    auto alloc = [&](size_t bytes) { char* r = w; w += (bytes + 255) & ~(size_t)255; return r; };
    unsigned char* feat8   = (unsigned char*)alloc((size_t)N * FEAT_ALL);
    float2*        elsc    = (float2*)alloc((size_t)N * HEADS * sizeof(float2));
    float*         er      = (float*)alloc((size_t)N * HEADS * sizeof(float));
    unsigned int*  ds      = (unsigned int*)alloc((size_t)E * 4);
    unsigned int*  srt     = (unsigned int*)alloc((size_t)E * 4);
    int*           hist    = (int*)alloc((size_t)NBLK1 * nbkt * 4);
    int*           base1   = (int*)alloc((size_t)NBLK1 * nbkt * 4);
    int*           tot     = (int*)alloc((size_t)nbkt * 4);

    const int nG = (N + 63) / 64;
    k1_fused<<<nG + NBLK1, 256, 0, stream>>>(src, dst, E, che, nbkt, ds, hist,
                                             h, W, attn_l, attn_r,
                                             feat8, elsc, er, N, nG);
    s1_scan<<<nbkt, 256, 0, stream>>>(hist, base1, tot, nbkt);
    p2_place<<<NBLK1, 256, 0, stream>>>(ds, hist, base1, tot, srt, E, che, nbkt);

    const int nqb = 8 * (((nbkt + 7) / 8) * 4);            // (bucket,quarter) blocks
    k5_bkt<<<nqb, 256, 0, stream>>>(srt, tot, elsc, er, feat8, bias, out, N, nbkt);
}

// Round 14
// 177.755 us; speedup vs baseline: 2.1676x; 1.0643x over previous
//
#include <hip/hip_runtime.h>
#include <hip/hip_bf16.h>
#include <hip/hip_fp16.h>
#include <math.h>

// GAT forward — atomic-free CSR build; k5 with wave-private-LDS exp dedup.
// R27 (this round): cost model from R22/R24/R26 fits: gap ~2.5us/dispatch,
//      fixed harness ~80us, kernel work ~84us -> only WORK matters. k5
//      (51us, VALU 58%) computes each (edge,head) exp 4x redundantly.
//      Split: phase A = one exp per (edge,head) into wave-private LDS
//      (pre-scaled, + slot ids, + den); phase B = proven 4-edge FMA loop
//      reading exs/s from LDS. ~30% VALU cut. No early return (deg=0 for
//      invalid nodes) so the A/B __syncthreads is legal. s2 dropped (p2
//      local bb-scan = R26-proven; p3 local s0 reduction).
// R26 (REGRESS 189.2): k5_bkt fusion — 33% occupancy, 4x redundant segment
//      scans. Fusion rejected; also calibrated the cost model.
// R25 (REGRESS 385): grid.sync = 65us/barrier (fabric wall). Never spin-sync.
// R24 (WIN 177.6): LDS-staged p2/p3 (kept).
// R23 (REGRESS): 8-edge k5 — 4-edge/16-lane kept.
// R22 (WIN 183.1): counting-sort CSR replaced 1.6M device atomics.
// R19: per-(node,head)-scaled INT8 feat (absmax 1.95e-3 vs 6.5e-3) kept.
// History: R6 global few-cursor binning; R12 shfl-from-exited-lanes UB;
// R13 GEMM-first; R14/R15 head-split fail; R17 XCD-align null;
// R18/R20/R21 atomic tuning nulls.

#define NEG_SLOPE 0.2f
#define HEADS 4
#define FEAT_OUT 32
#define FEAT_ALL 128
#define IN_FEAT 128
#define KP 136        // LDS K-stride in halves (sf tile only)
#define NBLK1 512     // pack/hist + place blocks
#define NBKT_MAX 512  // max buckets (N<=65536 -> <=512)
#define CHE_MAX 3200  // max edges per p2 chunk (E=1.6M/512=3128)
#define CHB_MAX 6144  // max edges per bucket (Poisson(4096), +32 sigma)

typedef _Float16 half8 __attribute__((ext_vector_type(8)));
typedef float float4v __attribute__((ext_vector_type(4)));
typedef unsigned int uint4v __attribute__((ext_vector_type(4)));

__device__ __forceinline__ float leaky(float v) {
    return v > 0.f ? v : NEG_SLOPE * v;
}

// ---- L1 fused: blocks [0,nG) MFMA GEMM; blocks [nG, nG+NBLK1) pack+hist ----
__global__ __launch_bounds__(256) void k1_fused(
    const int* __restrict__ src, const int* __restrict__ dst, int E,
    int che, int nbkt,
    unsigned int* __restrict__ ds, int* __restrict__ hist,
    const float* __restrict__ h, const float* __restrict__ W,
    const float* __restrict__ attn_l, const float* __restrict__ attn_r,
    unsigned char* __restrict__ feat8, float2* __restrict__ elsc,
    float* __restrict__ er, int N, int nG) {
    __shared__ _Float16 sf[64 * KP];    // 17.4 KB; pack blocks reuse as hist
    const int t = threadIdx.x;

    if ((int)blockIdx.x >= nG) {
        // ---------- pack + per-block bucket histogram ----------
        const int blk = blockIdx.x - nG;        // 0..NBLK1-1
        int* hb = (int*)sf;                     // nbkt bins
        for (int i = t; i < nbkt; i += 256) hb[i] = 0;
        __syncthreads();
        const int e_lo = blk * che;
        int e_hi = e_lo + che; if (e_hi > E) e_hi = E;
        for (int e0 = e_lo + t * 4; e0 < e_hi; e0 += 1024) {
            if (e0 + 3 < e_hi) {
                uint4v s4 = *(const uint4v*)(src + e0);
                uint4v d4 = *(const uint4v*)(dst + e0);
                uint4v r;
#pragma unroll
                for (int j = 0; j < 4; j++) r[j] = (s4[j] << 16) | d4[j];
                *(uint4v*)(ds + e0) = r;
#pragma unroll
                for (int j = 0; j < 4; j++) atomicAdd(&hb[d4[j] >> 7], 1);
            } else {
                for (int e = e0; e < e_hi; ++e) {
                    unsigned s = (unsigned)src[e], d = (unsigned)dst[e];
                    ds[e] = (s << 16) | d;
                    atomicAdd(&hb[d >> 7], 1);
                }
            }
        }
        __syncthreads();
        // column-major hist: hist[b*NBLK1 + blk] (coalesced reads in s1)
        for (int i = t; i < nbkt; i += 256) hist[i * NBLK1 + blk] = hb[i];
        return;
    }

    // ---------- GEMM: feat = h@W + epilogue, operands streamed ----------
    const int n0 = blockIdx.x * 64;
    const int wv_ = t >> 6;
    const int lane = t & 63;
    const int m16 = lane & 15;
    const int quad = lane >> 4;
    const int rowA = wv_ * 16 + m16;
    int nA = n0 + rowA; if (nA > N - 1) nA = N - 1;   // clamp: pad rows never stored
    const float* hp = h + (size_t)nA * IN_FEAT + quad * 8;

    float4v acc[8];
#pragma unroll
    for (int i = 0; i < 8; i++) acc[i] = (float4v){0.f, 0.f, 0.f, 0.f};

#pragma unroll
    for (int k0 = 0; k0 < 128; k0 += 32) {
        float4 a0 = *(const float4*)(hp + k0);
        float4 a1 = *(const float4*)(hp + k0 + 4);
        half8 a;
        a[0] = (_Float16)a0.x; a[1] = (_Float16)a0.y;
        a[2] = (_Float16)a0.z; a[3] = (_Float16)a0.w;
        a[4] = (_Float16)a1.x; a[5] = (_Float16)a1.y;
        a[6] = (_Float16)a1.z; a[7] = (_Float16)a1.w;
        const float* wp = W + (size_t)(k0 + quad * 8) * FEAT_ALL + m16;
#pragma unroll
        for (int tN = 0; tN < 8; tN++) {
            const float* wpt = wp + tN * 16;
            half8 b;
            b[0] = (_Float16)wpt[0];
            b[1] = (_Float16)wpt[FEAT_ALL];
            b[2] = (_Float16)wpt[2 * FEAT_ALL];
            b[3] = (_Float16)wpt[3 * FEAT_ALL];
            b[4] = (_Float16)wpt[4 * FEAT_ALL];
            b[5] = (_Float16)wpt[5 * FEAT_ALL];
            b[6] = (_Float16)wpt[6 * FEAT_ALL];
            b[7] = (_Float16)wpt[7 * FEAT_ALL];
            acc[tN] = __builtin_amdgcn_mfma_f32_16x16x32_f16(a, b, acc[tN], 0, 0, 0);
        }
    }

#pragma unroll
    for (int tN = 0; tN < 8; tN++)
#pragma unroll
        for (int r = 0; r < 4; r++) {
            int row = wv_ * 16 + quad * 4 + r;   // C/D: col=lane&15, row=quad*4+reg
            sf[row * KP + tN * 16 + m16] = (_Float16)acc[tN][r];
        }
    __syncthreads();

    // fused epilogue: thread (r,hh) computes el/er/scale over its 32 feats,
    // then packs the same 32 feats to scaled int8.
    {
        int r = t >> 2, hh = t & 3;
        int n = n0 + r;
        if (n < N) {
            const _Float16* sp_ = &sf[r * KP + hh * FEAT_OUT];
            float sl = 0.f, sr = 0.f, mx = 0.f;
#pragma unroll
            for (int f = 0; f < FEAT_OUT; f++) {
                float v = (float)sp_[f];
                sl += v * attn_l[hh * FEAT_OUT + f];
                sr += v * attn_r[hh * FEAT_OUT + f];
                mx = fmaxf(mx, fabsf(v));
            }
            er[n * HEADS + hh] = sr;
            elsc[n * HEADS + hh] = make_float2(sl, mx * (1.f / 127.f));
            const float inv = mx > 0.f ? 127.f / mx : 0.f;
            unsigned int w[8];
#pragma unroll
            for (int k2 = 0; k2 < 8; k2++) {
                unsigned int wv = 0;
#pragma unroll
                for (int j = 0; j < 4; j++) {
                    float v = (float)sp_[k2 * 4 + j];
                    int q = __float2int_rn(v * inv);
                    wv |= ((unsigned int)(q & 0xff)) << (8 * j);
                }
                w[k2] = wv;
            }
            uint4* dp = (uint4*)(feat8 + (size_t)n * FEAT_ALL + hh * 32);
            dp[0] = make_uint4(w[0], w[1], w[2], w[3]);
            dp[1] = make_uint4(w[4], w[5], w[6], w[7]);
        }
    }
}

// ---- s1: per-bucket exclusive prefix over the 512 block histograms ----
__global__ __launch_bounds__(256) void s1_scan(
    const int* __restrict__ hist, int* __restrict__ base1,
    int* __restrict__ tot, int nbkt) {
    __shared__ int sm[256];
    const int b = blockIdx.x;       // bucket
    const int t = threadIdx.x;
    const int v0 = hist[b * NBLK1 + 2 * t];
    const int v1 = hist[b * NBLK1 + 2 * t + 1];
    const int s = v0 + v1;
    sm[t] = s; __syncthreads();
    for (int off = 1; off < 256; off <<= 1) {
        int x = (t >= off) ? sm[t - off] : 0;
        __syncthreads();
        sm[t] += x;
        __syncthreads();
    }
    const int excl = sm[t] - s;
    base1[(2 * t) * nbkt + b] = excl;         // row-major for p2
    base1[(2 * t + 1) * nbkt + b] = excl + v0;
    if (t == 255) tot[b] = sm[255];
}

// ---- p2: local bucket-base scan + LDS-staged place + linear copy-out ----
__global__ __launch_bounds__(256) void p2_place(
    const unsigned int* __restrict__ ds, const int* __restrict__ hist,
    const int* __restrict__ base1, const int* __restrict__ tot,
    unsigned int* __restrict__ srt, int E, int che, int nbkt) {
    __shared__ int cur[NBKT_MAX];
    __shared__ int gst[NBKT_MAX];
    __shared__ int bbloc[NBKT_MAX];
    __shared__ int sm[256];
    __shared__ unsigned int stage[CHE_MAX];
    __shared__ int gaddr[CHE_MAX];
    const int t = threadIdx.x;
    const int blk = blockIdx.x;
    const int e_lo = blk * che;
    int e_hi = e_lo + che; if (e_hi > E) e_hi = E;
    int cnt = e_hi - e_lo; if (cnt < 0) cnt = 0;

    // bbloc = exclusive scan of tot (local recompute; replaces s2 dispatch)
    {
        const int v0 = (2 * t < nbkt) ? tot[2 * t] : 0;
        const int v1 = (2 * t + 1 < nbkt) ? tot[2 * t + 1] : 0;
        const int s = v0 + v1;
        sm[t] = s; __syncthreads();
        for (int off = 1; off < 256; off <<= 1) {
            int x = (t >= off) ? sm[t - off] : 0;
            __syncthreads();
            sm[t] += x;
            __syncthreads();
        }
        const int excl = sm[t] - s;
        if (2 * t < nbkt) bbloc[2 * t] = excl;
        if (2 * t + 1 < nbkt) bbloc[2 * t + 1] = excl + v0;
    }
    __syncthreads();

    if (che <= CHE_MAX) {
        // local hist column -> exclusive prefix (2 elems/thread)
        const int b0 = 2 * t, b1 = 2 * t + 1;
        const int h0 = (b0 < nbkt) ? hist[b0 * NBLK1 + blk] : 0;
        const int h1 = (b1 < nbkt) ? hist[b1 * NBLK1 + blk] : 0;
        const int s = h0 + h1;
        sm[t] = s; __syncthreads();
        for (int off = 1; off < 256; off <<= 1) {
            int x = (t >= off) ? sm[t - off] : 0;
            __syncthreads();
            sm[t] += x;
            __syncthreads();
        }
        const int excl = sm[t] - s;
        if (b0 < nbkt) {
            cur[b0] = excl;
            gst[b0] = bbloc[b0] + base1[blk * nbkt + b0] - excl;   // gaddr = gst + r
        }
        if (b1 < nbkt) {
            cur[b1] = excl + h0;
            gst[b1] = bbloc[b1] + base1[blk * nbkt + b1] - (excl + h0);
        }
        __syncthreads();
        for (int e0 = e_lo + t * 4; e0 < e_hi; e0 += 1024) {
            if (e0 + 3 < e_hi) {
                uint4v q = *(const uint4v*)(ds + e0);
#pragma unroll
                for (int j = 0; j < 4; j++) {
                    int b = (int)(q[j] & 0xffffu) >> 7;
                    int r = atomicAdd(&cur[b], 1);
                    stage[r] = q[j];
                    gaddr[r] = gst[b] + r;
                }
            } else {
                for (int e = e0; e < e_hi; ++e) {
                    unsigned q = ds[e];
                    int b = (int)(q & 0xffffu) >> 7;
                    int r = atomicAdd(&cur[b], 1);
                    stage[r] = q;
                    gaddr[r] = gst[b] + r;
                }
            }
        }
        __syncthreads();
        for (int i = t; i < cnt; i += 256)
            srt[gaddr[i]] = stage[i];
    } else {
        // fallback: direct global scatter
        for (int i = t; i < nbkt; i += 256)
            cur[i] = bbloc[i] + base1[blk * nbkt + i];
        __syncthreads();
        for (int e = e_lo + t; e < e_hi; e += 256) {
            unsigned q = ds[e];
            int b = (int)(q & 0xffffu) >> 7;
            int idx = atomicAdd(&cur[b], 1);
            srt[idx] = q;
        }
    }
}

// ---- p3: per-bucket exact CSR (local s0) + LDS-staged slots16 output ----
__global__ __launch_bounds__(256) void p3_bucket(
    const unsigned int* __restrict__ srt, const int* __restrict__ tot,
    unsigned short* __restrict__ slots16, unsigned int* __restrict__ rpd,
    int N, int nbkt) {
    __shared__ int red[256];
    __shared__ int h2[128];
    __shared__ int nbuf[128];
    __shared__ unsigned short stage16[CHB_MAX];
    const int b = blockIdx.x;
    const int t = threadIdx.x;
    // s0 = sum tot[0..b-1] (local reduce; replaces s2/bb)
    int partial = 0;
    for (int i = t; i < b; i += 256) partial += tot[i];
    red[t] = partial; __syncthreads();
    for (int off = 128; off > 0; off >>= 1) {
        if (t < off) red[t] += red[t + off];
        __syncthreads();
    }
    const int s0 = red[0];
    const int M = tot[b];
    const int lo = b << 7;
    if (t < 128) h2[t] = 0;
    __syncthreads();
    for (int i = t; i < M; i += 256) {
        unsigned q = srt[s0 + i];
        atomicAdd(&h2[(int)(q & 0xffffu) - lo], 1);
    }
    __syncthreads();
    int hv = 0;
    if (t < 128) hv = h2[t];
    for (int off = 1; off < 128; off <<= 1) {
        int x = 0;
        if (t < 128 && t >= off) x = h2[t - off];
        __syncthreads();
        if (t < 128) h2[t] += x;
        __syncthreads();
    }
    if (t < 128) {
        const int excl = h2[t] - hv;
        nbuf[t] = excl;
        const int n = lo + t;
        if (n < N) {
            int dg = hv > 255 ? 255 : hv;
            rpd[n] = ((unsigned)(s0 + excl) << 8) | (unsigned)dg;
        }
    }
    __syncthreads();
    if (t < 128) h2[t] = nbuf[t];       // reset cursors to exclusive bases
    __syncthreads();
    if (M <= CHB_MAX) {
        for (int i = t; i < M; i += 256) {
            unsigned q = srt[s0 + i];
            int n7 = (int)(q & 0xffffu) - lo;
            int r = atomicAdd(&h2[n7], 1);
            stage16[r] = (unsigned short)(q >> 16);   // LDS scatter (cheap)
        }
        __syncthreads();
        for (int i = t; i < M; i += 256)              // coalesced 2B copy-out
            slots16[s0 + i] = stage16[i];
    } else {
        for (int i = t; i < M; i += 256) {
            unsigned q = srt[s0 + i];
            int n7 = (int)(q & 0xffffu) - lo;
            int r = atomicAdd(&h2[n7], 1);
            slots16[s0 + r] = (unsigned short)(q >> 16);
        }
    }
}

// ---- K5 v2: wave-per-node aggregate with wave-private-LDS exp dedup ----
// Phase A: lanes = 16 edges x 4 heads; ONE exp per (edge,head); store
// pre-scaled ex*scale + slot id in wave-private LDS; accumulate den.
// Phase B: proven 4-edge/16-lane FMA loop reading exs/s from LDS.
// No early return (invalid nodes run with deg=0) -> the barrier is legal.
__global__ __launch_bounds__(256) void k5_node(
    const unsigned int* __restrict__ rpd, const unsigned short* __restrict__ slots16,
    const float2* __restrict__ elsc, const float* __restrict__ er,
    const unsigned char* __restrict__ feat8, const float* __restrict__ bias,
    float* __restrict__ out, int N) {
    __shared__ float exbuf[4][1024];         // [wave][edge*4+head], 16 KB
    __shared__ unsigned short sldb[4][256];  // [wave][edge], 2 KB
    const int t = threadIdx.x;
    const int lane = t & 63;
    const int wv = t >> 6;
    const int p = blockIdx.x & 7;
    const int g = blockIdx.x >> 3;
    const int NPER = (N + 7) >> 3;
    const int hi = ((p + 1) * NPER < N) ? (p + 1) * NPER : N;
    const int n = p * NPER + g * 4 + wv;
    const bool valid = (n < hi);
    const unsigned rd = valid ? rpd[n] : 0u;
    const int deg = (int)(rd & 0xffu);
    const unsigned short* sp = slots16 + (rd >> 8);
    float* exw = exbuf[wv];
    unsigned short* slw = sldb[wv];

    // ---- phase A: per-(edge,head) exp ----
    const int e4 = lane >> 2;       // edge within group of 16
    const int hd = lane & 3;        // head
    const float ern = valid ? er[n * HEADS + hd] : 0.f;
    float den = 0.f;
    for (int i0 = 0; i0 < deg; i0 += 16) {
        const int i = i0 + e4;
        if (i < deg) {
            const int s = (int)sp[i];             // 4-lane broadcast
            const float2 es = elsc[s * HEADS + hd];
            const float ex = __expf(leaky(es.x + ern));
            exw[i * 4 + hd] = ex * es.y;          // pre-scaled
            if (hd == 0) slw[i] = (unsigned short)s;
            den += ex;
        }
    }
    den += __shfl_xor(den, 4);
    den += __shfl_xor(den, 8);
    den += __shfl_xor(den, 16);
    den += __shfl_xor(den, 32);     // lanes 0..3 hold den for heads 0..3
    __syncthreads();

    // ---- phase B: FMA loop (4 edges/iter, 16 lanes/edge) ----
    const int sub4 = lane >> 4;     // edge within group of 4
    const int q4 = lane & 15;       // feats 8q4 .. 8q4+7
    const int hh = q4 >> 2;         // head of those feats
    const unsigned char* fb = feat8 + q4 * 8;

    float acc[8];
#pragma unroll
    for (int j = 0; j < 8; j++) acc[j] = 0.f;

#pragma unroll 4
    for (int i = sub4; i < deg; i += 4) {
        const int s = (int)slw[i];                // LDS broadcast
        const float exs = exw[i * 4 + hh];        // LDS broadcast (4 lanes)
        uint2 u = *(const uint2*)(fb + (size_t)s * FEAT_ALL);
        union { uint2 v; signed char c[8]; } cv;
        cv.v = u;
        acc[0] += exs * (float)cv.c[0];
        acc[1] += exs * (float)cv.c[1];
        acc[2] += exs * (float)cv.c[2];
        acc[3] += exs * (float)cv.c[3];
        acc[4] += exs * (float)cv.c[4];
        acc[5] += exs * (float)cv.c[5];
        acc[6] += exs * (float)cv.c[6];
        acc[7] += exs * (float)cv.c[7];
    }

    // joint reduction over the 4 edge-subgroups
#pragma unroll
    for (int j = 0; j < 8; j++) {
        acc[j] += __shfl_xor(acc[j], 16);
        acc[j] += __shfl_xor(acc[j], 32);
    }
    const float denh = __shfl(den, hh);           // den for this lane's head
    const float idh = 1.f / fmaxf(denh, 1e-9f);

    // bias + relu (per head), then mean over heads (lanes q4, q4^4, q4^8, q4^12)
    const float4 b0 = ((const float4*)bias)[q4 * 2];
    const float4 b1 = ((const float4*)bias)[q4 * 2 + 1];
    float v[8];
    v[0] = fmaxf(acc[0] * idh + b0.x, 0.f); v[1] = fmaxf(acc[1] * idh + b0.y, 0.f);
    v[2] = fmaxf(acc[2] * idh + b0.z, 0.f); v[3] = fmaxf(acc[3] * idh + b0.w, 0.f);
    v[4] = fmaxf(acc[4] * idh + b1.x, 0.f); v[5] = fmaxf(acc[5] * idh + b1.y, 0.f);
    v[6] = fmaxf(acc[6] * idh + b1.z, 0.f); v[7] = fmaxf(acc[7] * idh + b1.w, 0.f);
#pragma unroll
    for (int j = 0; j < 8; j++) {
        v[j] += __shfl_xor(v[j], 4);
        v[j] += __shfl_xor(v[j], 8);
    }
    if (valid && lane < 4) {
        float4 o0 = make_float4(v[0] * 0.25f, v[1] * 0.25f, v[2] * 0.25f, v[3] * 0.25f);
        float4 o1 = make_float4(v[4] * 0.25f, v[5] * 0.25f, v[6] * 0.25f, v[7] * 0.25f);
        float* op = out + (size_t)n * FEAT_OUT + lane * 8;
        ((float4*)op)[0] = o0;
        ((float4*)op)[1] = o1;
    }
}

extern "C" void kernel_launch(void* const* d_in, const int* in_sizes, int n_in,
                              void* d_out, int out_size, void* d_ws, size_t ws_size,
                              hipStream_t stream) {
    const float* h      = (const float*)d_in[0];
    const float* W      = (const float*)d_in[1];
    const float* attn_l = (const float*)d_in[2];
    const float* attn_r = (const float*)d_in[3];
    const float* bias   = (const float*)d_in[4];
    const int*   src    = (const int*)d_in[5];
    const int*   dst    = (const int*)d_in[6];
    float* out = (float*)d_out;

    const int N = in_sizes[0] / IN_FEAT;
    const int E = in_sizes[5];
    const int nbkt = (N + 127) >> 7;                       // 391 for N=50000
    const int che = (((E + NBLK1 - 1) / NBLK1) + 3) & ~3;  // chunk edges, x4

    // workspace layout (256B-aligned slabs)
    char* w = (char*)d_ws;
    auto alloc = [&](size_t bytes) { char* r = w; w += (bytes + 255) & ~(size_t)255; return r; };
    unsigned char* feat8   = (unsigned char*)alloc((size_t)N * FEAT_ALL);
    float2*        elsc    = (float2*)alloc((size_t)N * HEADS * sizeof(float2));
    float*         er      = (float*)alloc((size_t)N * HEADS * sizeof(float));
    unsigned int*  rpd     = (unsigned int*)alloc((size_t)N * 4);
    unsigned int*  ds      = (unsigned int*)alloc((size_t)E * 4);
    unsigned int*  srt     = (unsigned int*)alloc((size_t)E * 4);
    unsigned short* slots16 = (unsigned short*)alloc((size_t)E * 2);
    int*           hist    = (int*)alloc((size_t)NBLK1 * nbkt * 4);
    int*           base1   = (int*)alloc((size_t)NBLK1 * nbkt * 4);
    int*           tot     = (int*)alloc((size_t)nbkt * 4);

    const int nG = (N + 63) / 64;
    k1_fused<<<nG + NBLK1, 256, 0, stream>>>(src, dst, E, che, nbkt, ds, hist,
                                             h, W, attn_l, attn_r,
                                             feat8, elsc, er, N, nG);
    s1_scan<<<nbkt, 256, 0, stream>>>(hist, base1, tot, nbkt);
    p2_place<<<NBLK1, 256, 0, stream>>>(ds, hist, base1, tot, srt, E, che, nbkt);
    p3_bucket<<<nbkt, 256, 0, stream>>>(srt, tot, slots16, rpd, N, nbkt);

    const int NPER = (N + 7) >> 3;
    const int nb5 = 8 * ((NPER + 3) / 4);
    k5_node<<<nb5, 256, 0, stream>>>(rpd, slots16, elsc, er, feat8, bias, out, N);
}